// Round 6
// baseline (412.279 us; speedup 1.0000x reference)
//
#include <hip/hip_runtime.h>
#include <hip/hip_bf16.h>
#include <hip/hip_fp16.h>

#define N_NODES 50000
#define N_EDGES 800000
#define E_FEAT 16

// ---------------------------------------------------------------------------
// in-degree histogram (int atomics)
__global__ void deg_kernel(const int* __restrict__ col, int* __restrict__ deg, int E) {
    int e = blockIdx.x * blockDim.x + threadIdx.x;
    if (e < E) atomicAdd(&deg[col[e]], 1);
}

// --- 3-kernel exclusive scan of deg -> off ---------------------------------
__global__ void scanA_kernel(const int* __restrict__ deg, int* __restrict__ off,
                             int* __restrict__ blockSums, int N) {
    __shared__ int s[256];
    int i = blockIdx.x * 256 + threadIdx.x;
    s[threadIdx.x] = (i < N) ? deg[i] : 0;
    __syncthreads();
#pragma unroll
    for (int d = 1; d < 256; d <<= 1) {
        int t = (threadIdx.x >= d) ? s[threadIdx.x - d] : 0;
        __syncthreads();
        s[threadIdx.x] += t;
        __syncthreads();
    }
    if (i < N) off[i] = s[threadIdx.x];                 // inclusive within block
    if (threadIdx.x == 255) blockSums[blockIdx.x] = s[255];
}

__global__ void scanB_kernel(int* __restrict__ blockSums, int nb) {
    __shared__ int s[256];
    int t = threadIdx.x;
    int orig = (t < nb) ? blockSums[t] : 0;
    s[t] = orig;
    __syncthreads();
#pragma unroll
    for (int d = 1; d < 256; d <<= 1) {
        int v = (t >= d) ? s[t - d] : 0;
        __syncthreads();
        s[t] += v;
        __syncthreads();
    }
    if (t < nb) blockSums[t] = s[t] - orig;             // exclusive
}

// off -> global exclusive scan; dinv = rsqrt(deg+1); cnt = scatter cursor init
__global__ void scanC_kernel(const int* __restrict__ deg, int* __restrict__ off,
                             const int* __restrict__ blockSums, float* __restrict__ dinv,
                             int* __restrict__ cnt, int N) {
    int i = blockIdx.x * 256 + threadIdx.x;
    if (i >= N) return;
    int o = off[i] + blockSums[blockIdx.x] - deg[i];
    off[i] = o;
    cnt[i] = o;
    dinv[i] = rsqrtf((float)deg[i] + 1.0f);
}

// srcIdx[cnt[c]++] = row
__global__ void scatter_kernel(const int* __restrict__ row, const int* __restrict__ col,
                               int* __restrict__ cnt, int* __restrict__ srcIdx, int E) {
    int e = blockIdx.x * blockDim.x + threadIdx.x;
    if (e >= E) return;
    int pos = atomicAdd(&cnt[col[e]], 1);
    srcIdx[pos] = row[e];
}

// ---------------------------------------------------------------------------
// persistent GEMM, W column in VGPRs, X row via wave-uniform loads.
template <bool SCALE>
__global__ void gemm64_reg_kernel(const float* __restrict__ X, const float* __restrict__ W,
                                  const float* __restrict__ scale, __half* __restrict__ Y16,
                                  int N) {
    int lane = threadIdx.x & 63;
    float w[64];
#pragma unroll
    for (int k = 0; k < 64; ++k) w[k] = W[k * 64 + lane];
    int wid = (blockIdx.x * blockDim.x + threadIdx.x) >> 6;
    int nw = (gridDim.x * blockDim.x) >> 6;
    for (int r0 = wid; r0 < N; r0 += nw) {
        int r = __builtin_amdgcn_readfirstlane(r0);
        const float4* xr = (const float4*)(X + (size_t)r * 64);
        float acc = 0.0f;
#pragma unroll
        for (int k4 = 0; k4 < 16; ++k4) {
            float4 xv = xr[k4];
            acc = fmaf(xv.x, w[4 * k4 + 0], acc);
            acc = fmaf(xv.y, w[4 * k4 + 1], acc);
            acc = fmaf(xv.z, w[4 * k4 + 2], acc);
            acc = fmaf(xv.w, w[4 * k4 + 3], acc);
        }
        if (SCALE) acc *= scale[r];
        Y16[(size_t)r * 64 + lane] = __float2half_rn(acc);
    }
}

// dual persistent GEMM: P16 = half(X@WA + biasP), Q16 = half(X@WB)
__global__ void gemmPQ_reg_kernel(const float* __restrict__ X, const float* __restrict__ WA,
                                  const float* __restrict__ WB, const float* __restrict__ biasP,
                                  __half* __restrict__ P16, __half* __restrict__ Q16, int N) {
    int lane = threadIdx.x & 63;
    float wa[64], wb[64];
#pragma unroll
    for (int k = 0; k < 64; ++k) wa[k] = WA[k * 64 + lane];
#pragma unroll
    for (int k = 0; k < 64; ++k) wb[k] = WB[k * 64 + lane];
    float bp = biasP[lane];
    int wid = (blockIdx.x * blockDim.x + threadIdx.x) >> 6;
    int nw = (gridDim.x * blockDim.x) >> 6;
    for (int r0 = wid; r0 < N; r0 += nw) {
        int r = __builtin_amdgcn_readfirstlane(r0);
        const float4* xr = (const float4*)(X + (size_t)r * 64);
        float accP = bp, accQ = 0.0f;
#pragma unroll
        for (int k4 = 0; k4 < 16; ++k4) {
            float4 xv = xr[k4];
            accP = fmaf(xv.x, wa[4 * k4 + 0], accP); accQ = fmaf(xv.x, wb[4 * k4 + 0], accQ);
            accP = fmaf(xv.y, wa[4 * k4 + 1], accP); accQ = fmaf(xv.y, wb[4 * k4 + 1], accQ);
            accP = fmaf(xv.z, wa[4 * k4 + 2], accP); accQ = fmaf(xv.z, wb[4 * k4 + 2], accQ);
            accP = fmaf(xv.w, wa[4 * k4 + 3], accP); accQ = fmaf(xv.w, wb[4 * k4 + 3], accQ);
        }
        P16[(size_t)r * 64 + lane] = __float2half_rn(accP);
        Q16[(size_t)r * 64 + lane] = __float2half_rn(accQ);
    }
}

// ---------------------------------------------------------------------------
// CSR segment-sum + finalize. Wave = 4 groups of 16 lanes; group g handles
// edges j ≡ g (mod 4); lane sub owns features 4sub..4sub+3 (one 8B fp16x4
// gather per edge). 2 gathers in flight per group. Cross-group shfl reduce.
template <bool RELU>
__global__ void agg_csr_kernel(const float2* __restrict__ hs4,
                               const int* __restrict__ off, const int* __restrict__ deg,
                               const int* __restrict__ srcIdx,
                               const float* __restrict__ dinv, const float* __restrict__ b,
                               float4* __restrict__ out, int N) {
    int lane = threadIdx.x & 63;
    int n = blockIdx.x * (blockDim.x >> 6) + (threadIdx.x >> 6);
    if (n >= N) return;
    int g = lane >> 4;
    int sub = lane & 15;
    int o = off[n];
    int d = deg[n];
    float4 acc = make_float4(0.f, 0.f, 0.f, 0.f);
    if (g == 0) {                                        // self loop once
        float2 raw = hs4[(size_t)n * 16 + sub];
        float2 a01 = __half22float2(*(const __half2*)&raw.x);
        float2 a23 = __half22float2(*(const __half2*)&raw.y);
        acc.x = a01.x; acc.y = a01.y; acc.z = a23.x; acc.w = a23.y;
    }
    int j = g;
    for (; j + 4 < d; j += 8) {                          // 2 gathers in flight / group
        int s0 = srcIdx[o + j];
        int s1 = srcIdx[o + j + 4];
        float2 v0 = hs4[(size_t)s0 * 16 + sub];
        float2 v1 = hs4[(size_t)s1 * 16 + sub];
        float2 a01 = __half22float2(*(const __half2*)&v0.x);
        float2 a23 = __half22float2(*(const __half2*)&v0.y);
        float2 b01 = __half22float2(*(const __half2*)&v1.x);
        float2 b23 = __half22float2(*(const __half2*)&v1.y);
        acc.x += a01.x + b01.x; acc.y += a01.y + b01.y;
        acc.z += a23.x + b23.x; acc.w += a23.y + b23.y;
    }
    for (; j < d; j += 4) {
        float2 v = hs4[(size_t)srcIdx[o + j] * 16 + sub];
        float2 a01 = __half22float2(*(const __half2*)&v.x);
        float2 a23 = __half22float2(*(const __half2*)&v.y);
        acc.x += a01.x; acc.y += a01.y; acc.z += a23.x; acc.w += a23.y;
    }
    acc.x += __shfl_xor(acc.x, 16); acc.y += __shfl_xor(acc.y, 16);
    acc.z += __shfl_xor(acc.z, 16); acc.w += __shfl_xor(acc.w, 16);
    acc.x += __shfl_xor(acc.x, 32); acc.y += __shfl_xor(acc.y, 32);
    acc.z += __shfl_xor(acc.z, 32); acc.w += __shfl_xor(acc.w, 32);
    if (g == 0) {
        float dv = dinv[n];
        float4 bb = ((const float4*)b)[sub];
        float4 v;
        v.x = dv * acc.x + bb.x; v.y = dv * acc.y + bb.y;
        v.z = dv * acc.z + bb.z; v.w = dv * acc.w + bb.w;
        if (RELU) {
            v.x = fmaxf(v.x, 0.f); v.y = fmaxf(v.y, 0.f);
            v.z = fmaxf(v.z, 0.f); v.w = fmaxf(v.w, 0.f);
        }
        out[(size_t)n * 16 + sub] = v;
    }
}

// ---------------------------------------------------------------------------
// edge MLP, persistent, 2 edges unrolled per slot-iteration; C rows read from
// global (L1-hot, 4KB) and shared between the two edges.
__global__ __launch_bounds__(256, 6)
void edge_mlp3_kernel(const float2* __restrict__ P2, const float2* __restrict__ Q2,
                      const int* __restrict__ row, const int* __restrict__ col,
                      const float4* __restrict__ eAtt4,
                      const float* __restrict__ mW1,
                      const float* __restrict__ mW2, const float* __restrict__ mb2,
                      float* __restrict__ out, int E) {
    int sub = threadIdx.x & 15;
    const float4* Crow = (const float4*)(mW1 + 128 * 64);   // [16][16] float4 view
    float4 w2 = ((const float4*)mW2)[sub];
    float b2v = mb2[0];

    int slot = blockIdx.x * (blockDim.x >> 4) + (threadIdx.x >> 4);
    int nslots = gridDim.x * (blockDim.x >> 4);

    int e = slot;
    for (; e + nslots < E; e += 2 * nslots) {
        int e2 = e + nslots;
        int r1 = row[e],  c1 = col[e];
        int r2 = row[e2], c2 = col[e2];
        float2 praw1 = P2[(size_t)r1 * 16 + sub];
        float2 qraw1 = Q2[(size_t)c1 * 16 + sub];
        float2 praw2 = P2[(size_t)r2 * 16 + sub];
        float2 qraw2 = Q2[(size_t)c2 * 16 + sub];
        float4 eA1 = eAtt4[(size_t)e * 4 + 0],  eB1 = eAtt4[(size_t)e * 4 + 1];
        float4 eC1 = eAtt4[(size_t)e * 4 + 2],  eD1 = eAtt4[(size_t)e * 4 + 3];
        float4 eA2 = eAtt4[(size_t)e2 * 4 + 0], eB2 = eAtt4[(size_t)e2 * 4 + 1];
        float4 eC2 = eAtt4[(size_t)e2 * 4 + 2], eD2 = eAtt4[(size_t)e2 * 4 + 3];

        float2 p01 = __half22float2(*(const __half2*)&praw1.x);
        float2 p23 = __half22float2(*(const __half2*)&praw1.y);
        float2 q01 = __half22float2(*(const __half2*)&qraw1.x);
        float2 q23 = __half22float2(*(const __half2*)&qraw1.y);
        float4 acc1;
        acc1.x = p01.x + q01.x; acc1.y = p01.y + q01.y;
        acc1.z = p23.x + q23.x; acc1.w = p23.y + q23.y;
        p01 = __half22float2(*(const __half2*)&praw2.x);
        p23 = __half22float2(*(const __half2*)&praw2.y);
        q01 = __half22float2(*(const __half2*)&qraw2.x);
        q23 = __half22float2(*(const __half2*)&qraw2.y);
        float4 acc2;
        acc2.x = p01.x + q01.x; acc2.y = p01.y + q01.y;
        acc2.z = p23.x + q23.x; acc2.w = p23.y + q23.y;

        float ea1[16] = {eA1.x, eA1.y, eA1.z, eA1.w, eB1.x, eB1.y, eB1.z, eB1.w,
                         eC1.x, eC1.y, eC1.z, eC1.w, eD1.x, eD1.y, eD1.z, eD1.w};
        float ea2[16] = {eA2.x, eA2.y, eA2.z, eA2.w, eB2.x, eB2.y, eB2.z, eB2.w,
                         eC2.x, eC2.y, eC2.z, eC2.w, eD2.x, eD2.y, eD2.z, eD2.w};
#pragma unroll
        for (int k = 0; k < 16; ++k) {
            float4 cv = Crow[k * 16 + sub];
            acc1.x = fmaf(ea1[k], cv.x, acc1.x); acc2.x = fmaf(ea2[k], cv.x, acc2.x);
            acc1.y = fmaf(ea1[k], cv.y, acc1.y); acc2.y = fmaf(ea2[k], cv.y, acc2.y);
            acc1.z = fmaf(ea1[k], cv.z, acc1.z); acc2.z = fmaf(ea2[k], cv.z, acc2.z);
            acc1.w = fmaf(ea1[k], cv.w, acc1.w); acc2.w = fmaf(ea2[k], cv.w, acc2.w);
        }
        float t1 = fmaxf(acc1.x, 0.f) * w2.x + fmaxf(acc1.y, 0.f) * w2.y
                 + fmaxf(acc1.z, 0.f) * w2.z + fmaxf(acc1.w, 0.f) * w2.w;
        float t2 = fmaxf(acc2.x, 0.f) * w2.x + fmaxf(acc2.y, 0.f) * w2.y
                 + fmaxf(acc2.z, 0.f) * w2.z + fmaxf(acc2.w, 0.f) * w2.w;
        t1 += __shfl_xor(t1, 1); t2 += __shfl_xor(t2, 1);
        t1 += __shfl_xor(t1, 2); t2 += __shfl_xor(t2, 2);
        t1 += __shfl_xor(t1, 4); t2 += __shfl_xor(t2, 4);
        t1 += __shfl_xor(t1, 8); t2 += __shfl_xor(t2, 8);
        if (sub == 0) { out[e] = t1 + b2v; out[e2] = t2 + b2v; }
    }
    if (e < E) {
        int r1 = row[e], c1 = col[e];
        float2 praw1 = P2[(size_t)r1 * 16 + sub];
        float2 qraw1 = Q2[(size_t)c1 * 16 + sub];
        float4 eA1 = eAtt4[(size_t)e * 4 + 0], eB1 = eAtt4[(size_t)e * 4 + 1];
        float4 eC1 = eAtt4[(size_t)e * 4 + 2], eD1 = eAtt4[(size_t)e * 4 + 3];
        float2 p01 = __half22float2(*(const __half2*)&praw1.x);
        float2 p23 = __half22float2(*(const __half2*)&praw1.y);
        float2 q01 = __half22float2(*(const __half2*)&qraw1.x);
        float2 q23 = __half22float2(*(const __half2*)&qraw1.y);
        float4 acc1;
        acc1.x = p01.x + q01.x; acc1.y = p01.y + q01.y;
        acc1.z = p23.x + q23.x; acc1.w = p23.y + q23.y;
        float ea1[16] = {eA1.x, eA1.y, eA1.z, eA1.w, eB1.x, eB1.y, eB1.z, eB1.w,
                         eC1.x, eC1.y, eC1.z, eC1.w, eD1.x, eD1.y, eD1.z, eD1.w};
#pragma unroll
        for (int k = 0; k < 16; ++k) {
            float4 cv = Crow[k * 16 + sub];
            acc1.x = fmaf(ea1[k], cv.x, acc1.x);
            acc1.y = fmaf(ea1[k], cv.y, acc1.y);
            acc1.z = fmaf(ea1[k], cv.z, acc1.z);
            acc1.w = fmaf(ea1[k], cv.w, acc1.w);
        }
        float t1 = fmaxf(acc1.x, 0.f) * w2.x + fmaxf(acc1.y, 0.f) * w2.y
                 + fmaxf(acc1.z, 0.f) * w2.z + fmaxf(acc1.w, 0.f) * w2.w;
        t1 += __shfl_xor(t1, 1);
        t1 += __shfl_xor(t1, 2);
        t1 += __shfl_xor(t1, 4);
        t1 += __shfl_xor(t1, 8);
        if (sub == 0) out[e] = t1 + b2v;
    }
}

// ---------------------------------------------------------------------------
extern "C" void kernel_launch(void* const* d_in, const int* in_sizes, int n_in,
                              void* d_out, int out_size, void* d_ws, size_t ws_size,
                              hipStream_t stream) {
    const float* x    = (const float*)d_in[0];   // [N, 64]
    const int*   eIdx = (const int*)d_in[1];     // [2, E]
    const float* eAtt = (const float*)d_in[2];   // [E, 16]
    const float* W1   = (const float*)d_in[3];
    const float* b1   = (const float*)d_in[4];
    const float* W2   = (const float*)d_in[5];
    const float* b2   = (const float*)d_in[6];
    const float* mW1  = (const float*)d_in[7];   // [144,64]: A(0:64), B(64:128), C(128:144)
    const float* mb1  = (const float*)d_in[8];
    const float* mW2  = (const float*)d_in[9];
    const float* mb2  = (const float*)d_in[10];
    float* out = (float*)d_out;                  // [E]

    const int N = N_NODES;
    const int E = N_EDGES;
    const int* row = eIdx;
    const int* col = eIdx + E;

    // workspace layout (all offsets multiples of 16B)
    int*    deg_i  = (int*)d_ws;                        // N
    int*    cnt    = deg_i + N;                         // N
    int*    off    = cnt + N;                           // N
    int*    bsum   = off + N;                           // 256
    float*  dinv   = (float*)(bsum + 256);              // N
    int*    srcIdx = (int*)(dinv + N);                  // E
    __half* h16    = (__half*)(srcIdx + ((E + 63) & ~63)); // N*64*2 halves
    float*  bufB   = (float*)(h16 + (size_t)2 * N * 64);   // N*64 f32
    __half* P16    = h16;
    __half* Q16    = h16 + (size_t)N * 64;

    const int aggBlocks  = (N + 3) / 4;
    const int scanBlocks = (N + 255) / 256;

    // --- CSR build ---
    hipMemsetAsync(deg_i, 0, N * sizeof(int), stream);
    deg_kernel<<<(E + 255) / 256, 256, 0, stream>>>(col, deg_i, E);
    scanA_kernel<<<scanBlocks, 256, 0, stream>>>(deg_i, off, bsum, N);
    scanB_kernel<<<1, 256, 0, stream>>>(bsum, scanBlocks);
    scanC_kernel<<<scanBlocks, 256, 0, stream>>>(deg_i, off, bsum, dinv, cnt, N);
    scatter_kernel<<<(E + 255) / 256, 256, 0, stream>>>(row, col, cnt, srcIdx, E);

    // --- layer 1 ---
    gemm64_reg_kernel<true><<<1024, 256, 0, stream>>>(x, W1, dinv, h16, N);
    agg_csr_kernel<true><<<aggBlocks, 256, 0, stream>>>(
        (const float2*)h16, off, deg_i, srcIdx, dinv, b1, (float4*)bufB, N);

    // --- layer 2 ---
    gemm64_reg_kernel<true><<<1024, 256, 0, stream>>>(bufB, W2, dinv, h16, N);
    agg_csr_kernel<false><<<aggBlocks, 256, 0, stream>>>(
        (const float2*)h16, off, deg_i, srcIdx, dinv, b2, (float4*)bufB, N);

    // --- edge MLP decomposition: P16 = h2@A + mb1, Q16 = h2@B ---
    gemmPQ_reg_kernel<<<768, 256, 0, stream>>>(bufB, mW1, mW1 + 64 * 64, mb1, P16, Q16, N);

    edge_mlp3_kernel<<<3072, 256, 0, stream>>>(
        (const float2*)P16, (const float2*)Q16, row, col, (const float4*)eAtt,
        mW1, mW2, mb2, out, E);
}

// Round 7
// 280.232 us; speedup vs baseline: 1.4712x; 1.4712x over previous
//
#include <hip/hip_runtime.h>
#include <hip/hip_bf16.h>
#include <hip/hip_fp16.h>

#define N_NODES 50000
#define N_EDGES 800000
#define E_FEAT 16

typedef _Float16 half8_t __attribute__((ext_vector_type(8)));
typedef float f32x4 __attribute__((ext_vector_type(4)));

// ---------------------------------------------------------------------------
// in-degree histogram (int atomics)
__global__ void deg_kernel(const int* __restrict__ col, int* __restrict__ deg, int E) {
    int e = blockIdx.x * blockDim.x + threadIdx.x;
    if (e < E) atomicAdd(&deg[col[e]], 1);
}

// --- 3-kernel exclusive scan of deg -> off ---------------------------------
__global__ void scanA_kernel(const int* __restrict__ deg, int* __restrict__ off,
                             int* __restrict__ blockSums, int N) {
    __shared__ int s[256];
    int i = blockIdx.x * 256 + threadIdx.x;
    s[threadIdx.x] = (i < N) ? deg[i] : 0;
    __syncthreads();
#pragma unroll
    for (int d = 1; d < 256; d <<= 1) {
        int t = (threadIdx.x >= d) ? s[threadIdx.x - d] : 0;
        __syncthreads();
        s[threadIdx.x] += t;
        __syncthreads();
    }
    if (i < N) off[i] = s[threadIdx.x];                 // inclusive within block
    if (threadIdx.x == 255) blockSums[blockIdx.x] = s[255];
}

__global__ void scanB_kernel(int* __restrict__ blockSums, int nb) {
    __shared__ int s[256];
    int t = threadIdx.x;
    int orig = (t < nb) ? blockSums[t] : 0;
    s[t] = orig;
    __syncthreads();
#pragma unroll
    for (int d = 1; d < 256; d <<= 1) {
        int v = (t >= d) ? s[t - d] : 0;
        __syncthreads();
        s[t] += v;
        __syncthreads();
    }
    if (t < nb) blockSums[t] = s[t] - orig;             // exclusive
}

// off -> global exclusive scan; dinv = rsqrt(deg+1); cnt = scatter cursor init
__global__ void scanC_kernel(const int* __restrict__ deg, int* __restrict__ off,
                             const int* __restrict__ blockSums, float* __restrict__ dinv,
                             int* __restrict__ cnt, int N) {
    int i = blockIdx.x * 256 + threadIdx.x;
    if (i >= N) return;
    int o = off[i] + blockSums[blockIdx.x] - deg[i];
    off[i] = o;
    cnt[i] = o;
    dinv[i] = rsqrtf((float)deg[i] + 1.0f);
}

// srcIdx[cnt[c]++] = row
__global__ void scatter_kernel(const int* __restrict__ row, const int* __restrict__ col,
                               int* __restrict__ cnt, int* __restrict__ srcIdx, int E) {
    int e = blockIdx.x * blockDim.x + threadIdx.x;
    if (e >= E) return;
    int pos = atomicAdd(&cnt[col[e]], 1);
    srcIdx[pos] = row[e];
}

// ---------------------------------------------------------------------------
// persistent GEMM, W column in VGPRs, X row via wave-uniform loads.
template <bool SCALE>
__global__ void gemm64_reg_kernel(const float* __restrict__ X, const float* __restrict__ W,
                                  const float* __restrict__ scale, __half* __restrict__ Y16,
                                  int N) {
    int lane = threadIdx.x & 63;
    float w[64];
#pragma unroll
    for (int k = 0; k < 64; ++k) w[k] = W[k * 64 + lane];
    int wid = (blockIdx.x * blockDim.x + threadIdx.x) >> 6;
    int nw = (gridDim.x * blockDim.x) >> 6;
    for (int r0 = wid; r0 < N; r0 += nw) {
        int r = __builtin_amdgcn_readfirstlane(r0);
        const float4* xr = (const float4*)(X + (size_t)r * 64);
        float acc = 0.0f;
#pragma unroll
        for (int k4 = 0; k4 < 16; ++k4) {
            float4 xv = xr[k4];
            acc = fmaf(xv.x, w[4 * k4 + 0], acc);
            acc = fmaf(xv.y, w[4 * k4 + 1], acc);
            acc = fmaf(xv.z, w[4 * k4 + 2], acc);
            acc = fmaf(xv.w, w[4 * k4 + 3], acc);
        }
        if (SCALE) acc *= scale[r];
        Y16[(size_t)r * 64 + lane] = __float2half_rn(acc);
    }
}

// dual persistent GEMM: P16 = half(X@WA + biasP), Q16 = half(X@WB)
__global__ void gemmPQ_reg_kernel(const float* __restrict__ X, const float* __restrict__ WA,
                                  const float* __restrict__ WB, const float* __restrict__ biasP,
                                  __half* __restrict__ P16, __half* __restrict__ Q16, int N) {
    int lane = threadIdx.x & 63;
    float wa[64], wb[64];
#pragma unroll
    for (int k = 0; k < 64; ++k) wa[k] = WA[k * 64 + lane];
#pragma unroll
    for (int k = 0; k < 64; ++k) wb[k] = WB[k * 64 + lane];
    float bp = biasP[lane];
    int wid = (blockIdx.x * blockDim.x + threadIdx.x) >> 6;
    int nw = (gridDim.x * blockDim.x) >> 6;
    for (int r0 = wid; r0 < N; r0 += nw) {
        int r = __builtin_amdgcn_readfirstlane(r0);
        const float4* xr = (const float4*)(X + (size_t)r * 64);
        float accP = bp, accQ = 0.0f;
#pragma unroll
        for (int k4 = 0; k4 < 16; ++k4) {
            float4 xv = xr[k4];
            accP = fmaf(xv.x, wa[4 * k4 + 0], accP); accQ = fmaf(xv.x, wb[4 * k4 + 0], accQ);
            accP = fmaf(xv.y, wa[4 * k4 + 1], accP); accQ = fmaf(xv.y, wb[4 * k4 + 1], accQ);
            accP = fmaf(xv.z, wa[4 * k4 + 2], accP); accQ = fmaf(xv.z, wb[4 * k4 + 2], accQ);
            accP = fmaf(xv.w, wa[4 * k4 + 3], accP); accQ = fmaf(xv.w, wb[4 * k4 + 3], accQ);
        }
        P16[(size_t)r * 64 + lane] = __float2half_rn(accP);
        Q16[(size_t)r * 64 + lane] = __float2half_rn(accQ);
    }
}

// ---------------------------------------------------------------------------
// CSR segment-sum + finalize. Wave = 4 groups of 16 lanes; group g handles
// edges j ≡ g (mod 4); lane sub owns features 4sub..4sub+3 (one 8B fp16x4
// gather per edge). 2 gathers in flight per group. Cross-group shfl reduce.
template <bool RELU>
__global__ void agg_csr_kernel(const float2* __restrict__ hs4,
                               const int* __restrict__ off, const int* __restrict__ deg,
                               const int* __restrict__ srcIdx,
                               const float* __restrict__ dinv, const float* __restrict__ b,
                               float4* __restrict__ out, int N) {
    int lane = threadIdx.x & 63;
    int n = blockIdx.x * (blockDim.x >> 6) + (threadIdx.x >> 6);
    if (n >= N) return;
    int g = lane >> 4;
    int sub = lane & 15;
    int o = off[n];
    int d = deg[n];
    float4 acc = make_float4(0.f, 0.f, 0.f, 0.f);
    if (g == 0) {                                        // self loop once
        float2 raw = hs4[(size_t)n * 16 + sub];
        float2 a01 = __half22float2(*(const __half2*)&raw.x);
        float2 a23 = __half22float2(*(const __half2*)&raw.y);
        acc.x = a01.x; acc.y = a01.y; acc.z = a23.x; acc.w = a23.y;
    }
    int j = g;
    for (; j + 4 < d; j += 8) {                          // 2 gathers in flight / group
        int s0 = srcIdx[o + j];
        int s1 = srcIdx[o + j + 4];
        float2 v0 = hs4[(size_t)s0 * 16 + sub];
        float2 v1 = hs4[(size_t)s1 * 16 + sub];
        float2 a01 = __half22float2(*(const __half2*)&v0.x);
        float2 a23 = __half22float2(*(const __half2*)&v0.y);
        float2 b01 = __half22float2(*(const __half2*)&v1.x);
        float2 b23 = __half22float2(*(const __half2*)&v1.y);
        acc.x += a01.x + b01.x; acc.y += a01.y + b01.y;
        acc.z += a23.x + b23.x; acc.w += a23.y + b23.y;
    }
    for (; j < d; j += 4) {
        float2 v = hs4[(size_t)srcIdx[o + j] * 16 + sub];
        float2 a01 = __half22float2(*(const __half2*)&v.x);
        float2 a23 = __half22float2(*(const __half2*)&v.y);
        acc.x += a01.x; acc.y += a01.y; acc.z += a23.x; acc.w += a23.y;
    }
    acc.x += __shfl_xor(acc.x, 16); acc.y += __shfl_xor(acc.y, 16);
    acc.z += __shfl_xor(acc.z, 16); acc.w += __shfl_xor(acc.w, 16);
    acc.x += __shfl_xor(acc.x, 32); acc.y += __shfl_xor(acc.y, 32);
    acc.z += __shfl_xor(acc.z, 32); acc.w += __shfl_xor(acc.w, 32);
    if (g == 0) {
        float dv = dinv[n];
        float4 bb = ((const float4*)b)[sub];
        float4 v;
        v.x = dv * acc.x + bb.x; v.y = dv * acc.y + bb.y;
        v.z = dv * acc.z + bb.z; v.w = dv * acc.w + bb.w;
        if (RELU) {
            v.x = fmaxf(v.x, 0.f); v.y = fmaxf(v.y, 0.f);
            v.z = fmaxf(v.z, 0.f); v.w = fmaxf(v.w, 0.f);
        }
        out[(size_t)n * 16 + sub] = v;
    }
}

// ---------------------------------------------------------------------------
// edge MLP via MFMA. One wave = 16 edges.
// D[m=hidden][n=edge] = A(C^T, in VGPRs) @ B(eAtt^T), 4 chunks of 16 hidden,
// K=32 (feats 0..15 real, 16..31 zero-padded).
// D layout (16x16): n = lane&15 (edge), m = (lane>>4)*4 + reg (hidden in chunk).
// Lane adds P[row[e]] + Q[col[e]] (8B fp16 gathers matching its 4 hidden),
// relu, dot with w2; cross-group shfl_xor reduce; lanes 0-15 write out.
__global__ void edge_mlp4_kernel(const __half* __restrict__ P16, const __half* __restrict__ Q16,
                                 const int* __restrict__ row, const int* __restrict__ col,
                                 const float4* __restrict__ eAtt4,
                                 const float* __restrict__ mW1,
                                 const float* __restrict__ mW2, const float* __restrict__ mb2,
                                 float* __restrict__ out, int E) {
    int lane = threadIdx.x & 63;
    int grp = lane >> 4;
    int sub = lane & 15;

    // A fragments: aC[c][i] = C[k = grp*8+i][hidden = c*16+sub], 0 for k>=16
    half8_t aC[4];
#pragma unroll
    for (int c = 0; c < 4; ++c) {
#pragma unroll
        for (int i = 0; i < 8; ++i) {
            int k = grp * 8 + i;
            aC[c][i] = (k < 16) ? (_Float16)mW1[(128 + k) * 64 + c * 16 + sub]
                                : (_Float16)0.f;
        }
    }
    // w2 for this lane's hidden units: c*16 + grp*4 + {0..3}
    float4 w2v[4];
#pragma unroll
    for (int c = 0; c < 4; ++c) w2v[c] = ((const float4*)mW2)[c * 4 + grp];
    float b2v = mb2[0];

    int wid = (blockIdx.x * blockDim.x + threadIdx.x) >> 6;
    int nw = (gridDim.x * blockDim.x) >> 6;
    const int ntiles = E >> 4;                     // E % 16 == 0

    for (int t = wid; t < ntiles; t += nw) {
        int e0 = t << 4;
        int e = e0 + sub;
        int r = row[e];
        int cc = col[e];

        // B fragment: bf[i] = eAtt[e][k = grp*8+i], 0 for k>=16
        half8_t bf;
        if (grp < 2) {
            float4 u = eAtt4[(size_t)e * 4 + grp * 2 + 0];
            float4 v = eAtt4[(size_t)e * 4 + grp * 2 + 1];
            bf[0] = (_Float16)u.x; bf[1] = (_Float16)u.y;
            bf[2] = (_Float16)u.z; bf[3] = (_Float16)u.w;
            bf[4] = (_Float16)v.x; bf[5] = (_Float16)v.y;
            bf[6] = (_Float16)v.z; bf[7] = (_Float16)v.w;
        } else {
#pragma unroll
            for (int i = 0; i < 8; ++i) bf[i] = (_Float16)0.f;
        }

        // gathers: this lane needs hidden units c*16 + grp*4 .. +3 of P[r], Q[cc]
        float2 pr0 = *(const float2*)(P16 + (size_t)r  * 64 +  0 + grp * 4);
        float2 pr1 = *(const float2*)(P16 + (size_t)r  * 64 + 16 + grp * 4);
        float2 pr2 = *(const float2*)(P16 + (size_t)r  * 64 + 32 + grp * 4);
        float2 pr3 = *(const float2*)(P16 + (size_t)r  * 64 + 48 + grp * 4);
        float2 qr0 = *(const float2*)(Q16 + (size_t)cc * 64 +  0 + grp * 4);
        float2 qr1 = *(const float2*)(Q16 + (size_t)cc * 64 + 16 + grp * 4);
        float2 qr2 = *(const float2*)(Q16 + (size_t)cc * 64 + 32 + grp * 4);
        float2 qr3 = *(const float2*)(Q16 + (size_t)cc * 64 + 48 + grp * 4);

        f32x4 zero = {0.f, 0.f, 0.f, 0.f};
        f32x4 d0 = __builtin_amdgcn_mfma_f32_16x16x32_f16(aC[0], bf, zero, 0, 0, 0);
        f32x4 d1 = __builtin_amdgcn_mfma_f32_16x16x32_f16(aC[1], bf, zero, 0, 0, 0);
        f32x4 d2 = __builtin_amdgcn_mfma_f32_16x16x32_f16(aC[2], bf, zero, 0, 0, 0);
        f32x4 d3 = __builtin_amdgcn_mfma_f32_16x16x32_f16(aC[3], bf, zero, 0, 0, 0);

        float tacc = 0.f;
        {
            float2 p01 = __half22float2(*(const __half2*)&pr0.x);
            float2 p23 = __half22float2(*(const __half2*)&pr0.y);
            float2 q01 = __half22float2(*(const __half2*)&qr0.x);
            float2 q23 = __half22float2(*(const __half2*)&qr0.y);
            tacc = fmaf(fmaxf(d0[0] + p01.x + q01.x, 0.f), w2v[0].x, tacc);
            tacc = fmaf(fmaxf(d0[1] + p01.y + q01.y, 0.f), w2v[0].y, tacc);
            tacc = fmaf(fmaxf(d0[2] + p23.x + q23.x, 0.f), w2v[0].z, tacc);
            tacc = fmaf(fmaxf(d0[3] + p23.y + q23.y, 0.f), w2v[0].w, tacc);
        }
        {
            float2 p01 = __half22float2(*(const __half2*)&pr1.x);
            float2 p23 = __half22float2(*(const __half2*)&pr1.y);
            float2 q01 = __half22float2(*(const __half2*)&qr1.x);
            float2 q23 = __half22float2(*(const __half2*)&qr1.y);
            tacc = fmaf(fmaxf(d1[0] + p01.x + q01.x, 0.f), w2v[1].x, tacc);
            tacc = fmaf(fmaxf(d1[1] + p01.y + q01.y, 0.f), w2v[1].y, tacc);
            tacc = fmaf(fmaxf(d1[2] + p23.x + q23.x, 0.f), w2v[1].z, tacc);
            tacc = fmaf(fmaxf(d1[3] + p23.y + q23.y, 0.f), w2v[1].w, tacc);
        }
        {
            float2 p01 = __half22float2(*(const __half2*)&pr2.x);
            float2 p23 = __half22float2(*(const __half2*)&pr2.y);
            float2 q01 = __half22float2(*(const __half2*)&qr2.x);
            float2 q23 = __half22float2(*(const __half2*)&qr2.y);
            tacc = fmaf(fmaxf(d2[0] + p01.x + q01.x, 0.f), w2v[2].x, tacc);
            tacc = fmaf(fmaxf(d2[1] + p01.y + q01.y, 0.f), w2v[2].y, tacc);
            tacc = fmaf(fmaxf(d2[2] + p23.x + q23.x, 0.f), w2v[2].z, tacc);
            tacc = fmaf(fmaxf(d2[3] + p23.y + q23.y, 0.f), w2v[2].w, tacc);
        }
        {
            float2 p01 = __half22float2(*(const __half2*)&pr3.x);
            float2 p23 = __half22float2(*(const __half2*)&pr3.y);
            float2 q01 = __half22float2(*(const __half2*)&qr3.x);
            float2 q23 = __half22float2(*(const __half2*)&qr3.y);
            tacc = fmaf(fmaxf(d3[0] + p01.x + q01.x, 0.f), w2v[3].x, tacc);
            tacc = fmaf(fmaxf(d3[1] + p01.y + q01.y, 0.f), w2v[3].y, tacc);
            tacc = fmaf(fmaxf(d3[2] + p23.x + q23.x, 0.f), w2v[3].z, tacc);
            tacc = fmaf(fmaxf(d3[3] + p23.y + q23.y, 0.f), w2v[3].w, tacc);
        }
        tacc += __shfl_xor(tacc, 16);
        tacc += __shfl_xor(tacc, 32);
        if (grp == 0) out[e0 + sub] = tacc + b2v;
    }
}

// ---------------------------------------------------------------------------
extern "C" void kernel_launch(void* const* d_in, const int* in_sizes, int n_in,
                              void* d_out, int out_size, void* d_ws, size_t ws_size,
                              hipStream_t stream) {
    const float* x    = (const float*)d_in[0];   // [N, 64]
    const int*   eIdx = (const int*)d_in[1];     // [2, E]
    const float* eAtt = (const float*)d_in[2];   // [E, 16]
    const float* W1   = (const float*)d_in[3];
    const float* b1   = (const float*)d_in[4];
    const float* W2   = (const float*)d_in[5];
    const float* b2   = (const float*)d_in[6];
    const float* mW1  = (const float*)d_in[7];   // [144,64]: A(0:64), B(64:128), C(128:144)
    const float* mb1  = (const float*)d_in[8];
    const float* mW2  = (const float*)d_in[9];
    const float* mb2  = (const float*)d_in[10];
    float* out = (float*)d_out;                  // [E]

    const int N = N_NODES;
    const int E = N_EDGES;
    const int* row = eIdx;
    const int* col = eIdx + E;

    // workspace layout (all offsets multiples of 16B)
    int*    deg_i  = (int*)d_ws;                        // N
    int*    cnt    = deg_i + N;                         // N
    int*    off    = cnt + N;                           // N
    int*    bsum   = off + N;                           // 256
    float*  dinv   = (float*)(bsum + 256);              // N
    int*    srcIdx = (int*)(dinv + N);                  // E
    __half* h16    = (__half*)(srcIdx + ((E + 63) & ~63)); // N*64*2 halves
    float*  bufB   = (float*)(h16 + (size_t)2 * N * 64);   // N*64 f32
    __half* P16    = h16;
    __half* Q16    = h16 + (size_t)N * 64;

    const int aggBlocks  = (N + 3) / 4;
    const int scanBlocks = (N + 255) / 256;

    // --- CSR build ---
    hipMemsetAsync(deg_i, 0, N * sizeof(int), stream);
    deg_kernel<<<(E + 255) / 256, 256, 0, stream>>>(col, deg_i, E);
    scanA_kernel<<<scanBlocks, 256, 0, stream>>>(deg_i, off, bsum, N);
    scanB_kernel<<<1, 256, 0, stream>>>(bsum, scanBlocks);
    scanC_kernel<<<scanBlocks, 256, 0, stream>>>(deg_i, off, bsum, dinv, cnt, N);
    scatter_kernel<<<(E + 255) / 256, 256, 0, stream>>>(row, col, cnt, srcIdx, E);

    // --- layer 1 ---
    gemm64_reg_kernel<true><<<1024, 256, 0, stream>>>(x, W1, dinv, h16, N);
    agg_csr_kernel<true><<<aggBlocks, 256, 0, stream>>>(
        (const float2*)h16, off, deg_i, srcIdx, dinv, b1, (float4*)bufB, N);

    // --- layer 2 ---
    gemm64_reg_kernel<true><<<1024, 256, 0, stream>>>(bufB, W2, dinv, h16, N);
    agg_csr_kernel<false><<<aggBlocks, 256, 0, stream>>>(
        (const float2*)h16, off, deg_i, srcIdx, dinv, b2, (float4*)bufB, N);

    // --- edge MLP decomposition: P16 = h2@A + mb1, Q16 = h2@B ---
    gemmPQ_reg_kernel<<<768, 256, 0, stream>>>(bufB, mW1, mW1 + 64 * 64, mb1, P16, Q16, N);

    edge_mlp4_kernel<<<2048, 256, 0, stream>>>(
        P16, Q16, row, col, (const float4*)eAtt,
        mW1, mW2, mb2, out, E);
}

// Round 8
// 250.451 us; speedup vs baseline: 1.6461x; 1.1189x over previous
//
#include <hip/hip_runtime.h>
#include <hip/hip_bf16.h>
#include <hip/hip_fp16.h>

#define N_NODES 50000
#define N_EDGES 800000
#define E_FEAT 16

typedef _Float16 half4_t __attribute__((ext_vector_type(4)));
typedef _Float16 half8_t __attribute__((ext_vector_type(8)));
typedef float f32x4 __attribute__((ext_vector_type(4)));

// ---------------------------------------------------------------------------
// in-degree histogram (int atomics)
__global__ void deg_kernel(const int* __restrict__ col, int* __restrict__ deg, int E) {
    int e = blockIdx.x * blockDim.x + threadIdx.x;
    if (e < E) atomicAdd(&deg[col[e]], 1);
}

// --- 3-kernel exclusive scan of deg -> off ---------------------------------
__global__ void scanA_kernel(const int* __restrict__ deg, int* __restrict__ off,
                             int* __restrict__ blockSums, int N) {
    __shared__ int s[256];
    int i = blockIdx.x * 256 + threadIdx.x;
    s[threadIdx.x] = (i < N) ? deg[i] : 0;
    __syncthreads();
#pragma unroll
    for (int d = 1; d < 256; d <<= 1) {
        int t = (threadIdx.x >= d) ? s[threadIdx.x - d] : 0;
        __syncthreads();
        s[threadIdx.x] += t;
        __syncthreads();
    }
    if (i < N) off[i] = s[threadIdx.x];                 // inclusive within block
    if (threadIdx.x == 255) blockSums[blockIdx.x] = s[255];
}

__global__ void scanB_kernel(int* __restrict__ blockSums, int nb) {
    __shared__ int s[256];
    int t = threadIdx.x;
    int orig = (t < nb) ? blockSums[t] : 0;
    s[t] = orig;
    __syncthreads();
#pragma unroll
    for (int d = 1; d < 256; d <<= 1) {
        int v = (t >= d) ? s[t - d] : 0;
        __syncthreads();
        s[t] += v;
        __syncthreads();
    }
    if (t < nb) blockSums[t] = s[t] - orig;             // exclusive
}

// off -> global exclusive scan; dinv = rsqrt(deg+1); cnt = scatter cursor init
__global__ void scanC_kernel(const int* __restrict__ deg, int* __restrict__ off,
                             const int* __restrict__ blockSums, float* __restrict__ dinv,
                             int* __restrict__ cnt, int N) {
    int i = blockIdx.x * 256 + threadIdx.x;
    if (i >= N) return;
    int o = off[i] + blockSums[blockIdx.x] - deg[i];
    off[i] = o;
    cnt[i] = o;
    dinv[i] = rsqrtf((float)deg[i] + 1.0f);
}

// srcIdx[cnt[c]++] = row
__global__ void scatter_kernel(const int* __restrict__ row, const int* __restrict__ col,
                               int* __restrict__ cnt, int* __restrict__ srcIdx, int E) {
    int e = blockIdx.x * blockDim.x + threadIdx.x;
    if (e >= E) return;
    int pos = atomicAdd(&cnt[col[e]], 1);
    srcIdx[pos] = row[e];
}

// ---------------------------------------------------------------------------
// persistent GEMM, W column in VGPRs, X row via wave-uniform loads.
template <bool SCALE>
__global__ void gemm64_reg_kernel(const float* __restrict__ X, const float* __restrict__ W,
                                  const float* __restrict__ scale, __half* __restrict__ Y16,
                                  int N) {
    int lane = threadIdx.x & 63;
    float w[64];
#pragma unroll
    for (int k = 0; k < 64; ++k) w[k] = W[k * 64 + lane];
    int wid = (blockIdx.x * blockDim.x + threadIdx.x) >> 6;
    int nw = (gridDim.x * blockDim.x) >> 6;
    for (int r0 = wid; r0 < N; r0 += nw) {
        int r = __builtin_amdgcn_readfirstlane(r0);
        const float4* xr = (const float4*)(X + (size_t)r * 64);
        float acc = 0.0f;
#pragma unroll
        for (int k4 = 0; k4 < 16; ++k4) {
            float4 xv = xr[k4];
            acc = fmaf(xv.x, w[4 * k4 + 0], acc);
            acc = fmaf(xv.y, w[4 * k4 + 1], acc);
            acc = fmaf(xv.z, w[4 * k4 + 2], acc);
            acc = fmaf(xv.w, w[4 * k4 + 3], acc);
        }
        if (SCALE) acc *= scale[r];
        Y16[(size_t)r * 64 + lane] = __float2half_rn(acc);
    }
}

// dual persistent GEMM: P16 = half(X@WA + biasP), Q16 = half(X@WB)
__global__ void gemmPQ_reg_kernel(const float* __restrict__ X, const float* __restrict__ WA,
                                  const float* __restrict__ WB, const float* __restrict__ biasP,
                                  __half* __restrict__ P16, __half* __restrict__ Q16, int N) {
    int lane = threadIdx.x & 63;
    float wa[64], wb[64];
#pragma unroll
    for (int k = 0; k < 64; ++k) wa[k] = WA[k * 64 + lane];
#pragma unroll
    for (int k = 0; k < 64; ++k) wb[k] = WB[k * 64 + lane];
    float bp = biasP[lane];
    int wid = (blockIdx.x * blockDim.x + threadIdx.x) >> 6;
    int nw = (gridDim.x * blockDim.x) >> 6;
    for (int r0 = wid; r0 < N; r0 += nw) {
        int r = __builtin_amdgcn_readfirstlane(r0);
        const float4* xr = (const float4*)(X + (size_t)r * 64);
        float accP = bp, accQ = 0.0f;
#pragma unroll
        for (int k4 = 0; k4 < 16; ++k4) {
            float4 xv = xr[k4];
            accP = fmaf(xv.x, wa[4 * k4 + 0], accP); accQ = fmaf(xv.x, wb[4 * k4 + 0], accQ);
            accP = fmaf(xv.y, wa[4 * k4 + 1], accP); accQ = fmaf(xv.y, wb[4 * k4 + 1], accQ);
            accP = fmaf(xv.z, wa[4 * k4 + 2], accP); accQ = fmaf(xv.z, wb[4 * k4 + 2], accQ);
            accP = fmaf(xv.w, wa[4 * k4 + 3], accP); accQ = fmaf(xv.w, wb[4 * k4 + 3], accQ);
        }
        P16[(size_t)r * 64 + lane] = __float2half_rn(accP);
        Q16[(size_t)r * 64 + lane] = __float2half_rn(accQ);
    }
}

// ---------------------------------------------------------------------------
// CSR segment-sum + finalize. Wave = 4 groups of 16 lanes; group g handles
// edges j ≡ g (mod 4); lane sub owns features 4sub..4sub+3 (one 8B fp16x4
// gather per edge). Up to 4 gathers in flight per group.
template <bool RELU>
__global__ void agg_csr_kernel(const float2* __restrict__ hs4,
                               const int* __restrict__ off, const int* __restrict__ deg,
                               const int* __restrict__ srcIdx,
                               const float* __restrict__ dinv, const float* __restrict__ b,
                               float4* __restrict__ out, int N) {
    int lane = threadIdx.x & 63;
    int n = blockIdx.x * (blockDim.x >> 6) + (threadIdx.x >> 6);
    if (n >= N) return;
    int g = lane >> 4;
    int sub = lane & 15;
    int o = off[n];
    int d = deg[n];
    float4 acc = make_float4(0.f, 0.f, 0.f, 0.f);
    if (g == 0) {                                        // self loop once
        float2 raw = hs4[(size_t)n * 16 + sub];
        float2 a01 = __half22float2(*(const __half2*)&raw.x);
        float2 a23 = __half22float2(*(const __half2*)&raw.y);
        acc.x = a01.x; acc.y = a01.y; acc.z = a23.x; acc.w = a23.y;
    }
    int j = g;
    for (; j + 12 < d; j += 16) {                        // 4 gathers in flight / group
        int s0 = srcIdx[o + j],     s1 = srcIdx[o + j + 4];
        int s2 = srcIdx[o + j + 8], s3 = srcIdx[o + j + 12];
        float2 v0 = hs4[(size_t)s0 * 16 + sub];
        float2 v1 = hs4[(size_t)s1 * 16 + sub];
        float2 v2 = hs4[(size_t)s2 * 16 + sub];
        float2 v3 = hs4[(size_t)s3 * 16 + sub];
        float2 a01 = __half22float2(*(const __half2*)&v0.x);
        float2 a23 = __half22float2(*(const __half2*)&v0.y);
        float2 b01 = __half22float2(*(const __half2*)&v1.x);
        float2 b23 = __half22float2(*(const __half2*)&v1.y);
        float2 c01 = __half22float2(*(const __half2*)&v2.x);
        float2 c23 = __half22float2(*(const __half2*)&v2.y);
        float2 d01 = __half22float2(*(const __half2*)&v3.x);
        float2 d23 = __half22float2(*(const __half2*)&v3.y);
        acc.x += (a01.x + b01.x) + (c01.x + d01.x);
        acc.y += (a01.y + b01.y) + (c01.y + d01.y);
        acc.z += (a23.x + b23.x) + (c23.x + d23.x);
        acc.w += (a23.y + b23.y) + (c23.y + d23.y);
    }
    for (; j + 4 < d; j += 8) {                          // 2 in flight
        int s0 = srcIdx[o + j];
        int s1 = srcIdx[o + j + 4];
        float2 v0 = hs4[(size_t)s0 * 16 + sub];
        float2 v1 = hs4[(size_t)s1 * 16 + sub];
        float2 a01 = __half22float2(*(const __half2*)&v0.x);
        float2 a23 = __half22float2(*(const __half2*)&v0.y);
        float2 b01 = __half22float2(*(const __half2*)&v1.x);
        float2 b23 = __half22float2(*(const __half2*)&v1.y);
        acc.x += a01.x + b01.x; acc.y += a01.y + b01.y;
        acc.z += a23.x + b23.x; acc.w += a23.y + b23.y;
    }
    for (; j < d; j += 4) {
        float2 v = hs4[(size_t)srcIdx[o + j] * 16 + sub];
        float2 a01 = __half22float2(*(const __half2*)&v.x);
        float2 a23 = __half22float2(*(const __half2*)&v.y);
        acc.x += a01.x; acc.y += a01.y; acc.z += a23.x; acc.w += a23.y;
    }
    acc.x += __shfl_xor(acc.x, 16); acc.y += __shfl_xor(acc.y, 16);
    acc.z += __shfl_xor(acc.z, 16); acc.w += __shfl_xor(acc.w, 16);
    acc.x += __shfl_xor(acc.x, 32); acc.y += __shfl_xor(acc.y, 32);
    acc.z += __shfl_xor(acc.z, 32); acc.w += __shfl_xor(acc.w, 32);
    if (g == 0) {
        float dv = dinv[n];
        float4 bb = ((const float4*)b)[sub];
        float4 v;
        v.x = dv * acc.x + bb.x; v.y = dv * acc.y + bb.y;
        v.z = dv * acc.z + bb.z; v.w = dv * acc.w + bb.w;
        if (RELU) {
            v.x = fmaxf(v.x, 0.f); v.y = fmaxf(v.y, 0.f);
            v.z = fmaxf(v.z, 0.f); v.w = fmaxf(v.w, 0.f);
        }
        out[(size_t)n * 16 + sub] = v;
    }
}

// ---------------------------------------------------------------------------
// edge MLP via mfma_f32_16x16x16_f16 (K=16, no padding). One wave = 16 edges.
// Chunk c covers hidden units h = 4m + c (m = MFMA row):
//   A_c[m][k] = C[k][4m+c];  B[k][n] = eAtt[e0+n][k]
//   D_c[m][n] = (eAtt[e0+n] @ C)[4m+c]
// Fragments (lane l = grp*16+sub): A: m=sub, k=4grp+i; B: n=sub, k=4grp+i;
// D: n=sub, m=4grp+reg  =>  lane's hidden units h = 16grp + 4reg + c, i.e.
// halves 16grp..16grp+15 of P[row]/Q[col] — contiguous 32B, two 16B loads.
// P+Q fused as the MFMA C-operand.
__global__ void edge_mlp5_kernel(const __half* __restrict__ P16, const __half* __restrict__ Q16,
                                 const int* __restrict__ row, const int* __restrict__ col,
                                 const float4* __restrict__ eAtt4,
                                 const float* __restrict__ mW1,
                                 const float* __restrict__ mW2, const float* __restrict__ mb2,
                                 float* __restrict__ out, int E) {
    int lane = threadIdx.x & 63;
    int grp = lane >> 4;
    int sub = lane & 15;

    // A fragments: aC[c][i] = C[k=4grp+i][h=4sub+c]
    half4_t aC0, aC1, aC2, aC3;
#pragma unroll
    for (int i = 0; i < 4; ++i) {
        const float* crow = mW1 + (size_t)(128 + 4 * grp + i) * 64 + 4 * sub;
        aC0[i] = (_Float16)crow[0];
        aC1[i] = (_Float16)crow[1];
        aC2[i] = (_Float16)crow[2];
        aC3[i] = (_Float16)crow[3];
    }
    // w2 for this lane: mW2[16grp + 4j + c] = w2v[j] component c
    float4 w20 = ((const float4*)mW2)[4 * grp + 0];
    float4 w21 = ((const float4*)mW2)[4 * grp + 1];
    float4 w22 = ((const float4*)mW2)[4 * grp + 2];
    float4 w23 = ((const float4*)mW2)[4 * grp + 3];
    float b2v = mb2[0];

    int wid = (blockIdx.x * blockDim.x + threadIdx.x) >> 6;
    int nw = (gridDim.x * blockDim.x) >> 6;
    const int ntiles = E >> 4;                     // E % 16 == 0

    // prefetch first tile's indices
    int rN = 0, cN = 0;
    if (wid < ntiles) { rN = row[(wid << 4) + sub]; cN = col[(wid << 4) + sub]; }

    for (int t = wid; t < ntiles; t += nw) {
        int e0 = t << 4;
        int r = rN, cc = cN;
        int tn = t + nw;
        if (tn < ntiles) { rN = row[(tn << 4) + sub]; cN = col[(tn << 4) + sub]; }

        // B fragment: eAtt[e0+sub][4grp..4grp+3] — one 16B load per lane
        float4 ef = eAtt4[(size_t)e0 * 4 + (size_t)sub * 4 + grp];
        half4_t bf;
        bf[0] = (_Float16)ef.x; bf[1] = (_Float16)ef.y;
        bf[2] = (_Float16)ef.z; bf[3] = (_Float16)ef.w;

        // P/Q: halves 16grp..16grp+15 of row r / cc — two 16B loads each
        const half8_t* pr = (const half8_t*)(P16 + (size_t)r * 64 + grp * 16);
        const half8_t* qr = (const half8_t*)(Q16 + (size_t)cc * 64 + grp * 16);
        half8_t ph0 = pr[0], ph1 = pr[1];
        half8_t qh0 = qr[0], qh1 = qr[1];

        // C-in: cin_c[r] = P[h] + Q[h], h local idx 4r+c (r>=2 in *h1[idx-8])
        f32x4 cin0 = {(float)ph0[0] + (float)qh0[0], (float)ph0[4] + (float)qh0[4],
                      (float)ph1[0] + (float)qh1[0], (float)ph1[4] + (float)qh1[4]};
        f32x4 cin1 = {(float)ph0[1] + (float)qh0[1], (float)ph0[5] + (float)qh0[5],
                      (float)ph1[1] + (float)qh1[1], (float)ph1[5] + (float)qh1[5]};
        f32x4 cin2 = {(float)ph0[2] + (float)qh0[2], (float)ph0[6] + (float)qh0[6],
                      (float)ph1[2] + (float)qh1[2], (float)ph1[6] + (float)qh1[6]};
        f32x4 cin3 = {(float)ph0[3] + (float)qh0[3], (float)ph0[7] + (float)qh0[7],
                      (float)ph1[3] + (float)qh1[3], (float)ph1[7] + (float)qh1[7]};

        f32x4 d0 = __builtin_amdgcn_mfma_f32_16x16x16f16(aC0, bf, cin0, 0, 0, 0);
        f32x4 d1 = __builtin_amdgcn_mfma_f32_16x16x16f16(aC1, bf, cin1, 0, 0, 0);
        f32x4 d2 = __builtin_amdgcn_mfma_f32_16x16x16f16(aC2, bf, cin2, 0, 0, 0);
        f32x4 d3 = __builtin_amdgcn_mfma_f32_16x16x16f16(aC3, bf, cin3, 0, 0, 0);

        // t = sum over h of relu(hidden_h) * w2[h];  h = 16grp + 4r + c
        float tacc = fmaxf(d0[0], 0.f) * w20.x + fmaxf(d0[1], 0.f) * w21.x
                   + fmaxf(d0[2], 0.f) * w22.x + fmaxf(d0[3], 0.f) * w23.x;
        tacc += fmaxf(d1[0], 0.f) * w20.y + fmaxf(d1[1], 0.f) * w21.y
              + fmaxf(d1[2], 0.f) * w22.y + fmaxf(d1[3], 0.f) * w23.y;
        tacc += fmaxf(d2[0], 0.f) * w20.z + fmaxf(d2[1], 0.f) * w21.z
              + fmaxf(d2[2], 0.f) * w22.z + fmaxf(d2[3], 0.f) * w23.z;
        tacc += fmaxf(d3[0], 0.f) * w20.w + fmaxf(d3[1], 0.f) * w21.w
              + fmaxf(d3[2], 0.f) * w22.w + fmaxf(d3[3], 0.f) * w23.w;

        tacc += __shfl_xor(tacc, 16);
        tacc += __shfl_xor(tacc, 32);
        if (grp == 0) out[e0 + sub] = tacc + b2v;
    }
}

// ---------------------------------------------------------------------------
extern "C" void kernel_launch(void* const* d_in, const int* in_sizes, int n_in,
                              void* d_out, int out_size, void* d_ws, size_t ws_size,
                              hipStream_t stream) {
    const float* x    = (const float*)d_in[0];   // [N, 64]
    const int*   eIdx = (const int*)d_in[1];     // [2, E]
    const float* eAtt = (const float*)d_in[2];   // [E, 16]
    const float* W1   = (const float*)d_in[3];
    const float* b1   = (const float*)d_in[4];
    const float* W2   = (const float*)d_in[5];
    const float* b2   = (const float*)d_in[6];
    const float* mW1  = (const float*)d_in[7];   // [144,64]: A(0:64), B(64:128), C(128:144)
    const float* mb1  = (const float*)d_in[8];
    const float* mW2  = (const float*)d_in[9];
    const float* mb2  = (const float*)d_in[10];
    float* out = (float*)d_out;                  // [E]

    const int N = N_NODES;
    const int E = N_EDGES;
    const int* row = eIdx;
    const int* col = eIdx + E;

    // workspace layout (all offsets multiples of 16B)
    int*    deg_i  = (int*)d_ws;                        // N
    int*    cnt    = deg_i + N;                         // N
    int*    off    = cnt + N;                           // N
    int*    bsum   = off + N;                           // 256
    float*  dinv   = (float*)(bsum + 256);              // N
    int*    srcIdx = (int*)(dinv + N);                  // E
    __half* h16    = (__half*)(srcIdx + ((E + 63) & ~63)); // N*64*2 halves
    float*  bufB   = (float*)(h16 + (size_t)2 * N * 64);   // N*64 f32
    __half* P16    = h16;
    __half* Q16    = h16 + (size_t)N * 64;

    const int aggBlocks  = (N + 3) / 4;
    const int scanBlocks = (N + 255) / 256;

    // --- CSR build ---
    hipMemsetAsync(deg_i, 0, N * sizeof(int), stream);
    deg_kernel<<<(E + 255) / 256, 256, 0, stream>>>(col, deg_i, E);
    scanA_kernel<<<scanBlocks, 256, 0, stream>>>(deg_i, off, bsum, N);
    scanB_kernel<<<1, 256, 0, stream>>>(bsum, scanBlocks);
    scanC_kernel<<<scanBlocks, 256, 0, stream>>>(deg_i, off, bsum, dinv, cnt, N);
    scatter_kernel<<<(E + 255) / 256, 256, 0, stream>>>(row, col, cnt, srcIdx, E);

    // --- layer 1 ---
    gemm64_reg_kernel<true><<<1024, 256, 0, stream>>>(x, W1, dinv, h16, N);
    agg_csr_kernel<true><<<aggBlocks, 256, 0, stream>>>(
        (const float2*)h16, off, deg_i, srcIdx, dinv, b1, (float4*)bufB, N);

    // --- layer 2 ---
    gemm64_reg_kernel<true><<<1024, 256, 0, stream>>>(bufB, W2, dinv, h16, N);
    agg_csr_kernel<false><<<aggBlocks, 256, 0, stream>>>(
        (const float2*)h16, off, deg_i, srcIdx, dinv, b2, (float4*)bufB, N);

    // --- edge MLP decomposition: P16 = h2@A + mb1, Q16 = h2@B ---
    gemmPQ_reg_kernel<<<768, 256, 0, stream>>>(bufB, mW1, mW1 + 64 * 64, mb1, P16, Q16, N);

    edge_mlp5_kernel<<<2048, 256, 0, stream>>>(
        P16, Q16, row, col, (const float4*)eAtt,
        mW1, mW2, mb2, out, E);
}

// Round 9
// 206.550 us; speedup vs baseline: 1.9960x; 1.2125x over previous
//
#include <hip/hip_runtime.h>
#include <hip/hip_bf16.h>
#include <hip/hip_fp16.h>

#define N_NODES 50000
#define N_EDGES 800000
#define E_FEAT 16
#define NSLICE 8
#define SLICE_W 6250   // N_NODES / NSLICE exactly

typedef _Float16 half4_t __attribute__((ext_vector_type(4)));
typedef _Float16 half8_t __attribute__((ext_vector_type(8)));
typedef float f32x4 __attribute__((ext_vector_type(4)));

// ---------------------------------------------------------------------------
// in-degree histogram (int atomics)
__global__ void deg_kernel(const int* __restrict__ col, int* __restrict__ deg, int E) {
    int e = blockIdx.x * blockDim.x + threadIdx.x;
    if (e < E) atomicAdd(&deg[col[e]], 1);
}

// --- 3-kernel exclusive scan of deg -> off ---------------------------------
__global__ void scanA_kernel(const int* __restrict__ deg, int* __restrict__ off,
                             int* __restrict__ blockSums, int N) {
    __shared__ int s[256];
    int i = blockIdx.x * 256 + threadIdx.x;
    s[threadIdx.x] = (i < N) ? deg[i] : 0;
    __syncthreads();
#pragma unroll
    for (int d = 1; d < 256; d <<= 1) {
        int t = (threadIdx.x >= d) ? s[threadIdx.x - d] : 0;
        __syncthreads();
        s[threadIdx.x] += t;
        __syncthreads();
    }
    if (i < N) off[i] = s[threadIdx.x];                 // inclusive within block
    if (threadIdx.x == 255) blockSums[blockIdx.x] = s[255];
}

__global__ void scanB_kernel(int* __restrict__ blockSums, int nb) {
    __shared__ int s[256];
    int t = threadIdx.x;
    int orig = (t < nb) ? blockSums[t] : 0;
    s[t] = orig;
    __syncthreads();
#pragma unroll
    for (int d = 1; d < 256; d <<= 1) {
        int v = (t >= d) ? s[t - d] : 0;
        __syncthreads();
        s[t] += v;
        __syncthreads();
    }
    if (t < nb) blockSums[t] = s[t] - orig;             // exclusive
}

// off -> global exclusive scan; dinv = rsqrt(deg+1); cnt = scatter cursor init
__global__ void scanC_kernel(const int* __restrict__ deg, int* __restrict__ off,
                             const int* __restrict__ blockSums, float* __restrict__ dinv,
                             int* __restrict__ cnt, int N) {
    int i = blockIdx.x * 256 + threadIdx.x;
    if (i >= N) return;
    int o = off[i] + blockSums[blockIdx.x] - deg[i];
    off[i] = o;
    cnt[i] = o;
    dinv[i] = rsqrtf((float)deg[i] + 1.0f);
}

// XCD-sliced scatter: block b covers edge-chunk (b>>3) and col-slice (b&7).
// With the blockIdx%8 -> XCD round-robin, each srcIdx line / cnt counter is
// written by exactly one XCD -> dirty bytes coalesce in that XCD's L2.
// Correct for ANY block->XCD mapping (mapping affects only locality).
__global__ void scatter_slice_kernel(const int* __restrict__ row, const int* __restrict__ col,
                                     int* __restrict__ cnt, int* __restrict__ srcIdx, int E) {
    int slice = blockIdx.x & (NSLICE - 1);
    int chunk = blockIdx.x >> 3;
    int nch = gridDim.x >> 3;
    int lo = slice * SLICE_W;
    int hi = lo + SLICE_W;
    int stride = nch * blockDim.x * 4;
    for (int e0 = (chunk * blockDim.x + threadIdx.x) * 4; e0 < E; e0 += stride) {
        int4 c4 = *(const int4*)(col + e0);              // E % 4 == 0
        if (c4.x >= lo && c4.x < hi) { int p = atomicAdd(&cnt[c4.x], 1); srcIdx[p] = row[e0]; }
        if (c4.y >= lo && c4.y < hi) { int p = atomicAdd(&cnt[c4.y], 1); srcIdx[p] = row[e0 + 1]; }
        if (c4.z >= lo && c4.z < hi) { int p = atomicAdd(&cnt[c4.z], 1); srcIdx[p] = row[e0 + 2]; }
        if (c4.w >= lo && c4.w < hi) { int p = atomicAdd(&cnt[c4.w], 1); srcIdx[p] = row[e0 + 3]; }
    }
}

// ---------------------------------------------------------------------------
// MFMA node GEMM: Y16 = half( (X @ W) * (SCALE? dinv : 1) + (DUAL? bias : 0) )
// One wave = 16 rows, K=64, NF*16 output cols via mfma_f32_16x16x16_f16.
// Fragment convention (verified by edge_mlp5): lane = grp*16+sub;
//   A[m][k]: m=sub, k=4grp+i ; B[k][n]: n=sub, k=4grp+i ; D: n=sub, m=4grp+reg.
// DUAL: cols 0..63 from WA -> YA (+bias), cols 64..127 from WB -> YB.
template <int NF, bool SCALE, bool DUAL>
__global__ void gemm_mfma_kernel(const float* __restrict__ X,
                                 const float* __restrict__ WA, const float* __restrict__ WB,
                                 const float* __restrict__ scale, const float* __restrict__ bias,
                                 __half* __restrict__ YA, __half* __restrict__ YB, int N) {
    int lane = threadIdx.x & 63;
    int grp = lane >> 4, sub = lane & 15;

    half4_t wf[NF][4];
#pragma unroll
    for (int fc = 0; fc < NF; ++fc) {
        const float* Wsrc = (DUAL && fc >= NF / 2) ? WB : WA;
        int f = 16 * (DUAL ? (fc % (NF / 2)) : fc) + sub;
#pragma unroll
        for (int kc = 0; kc < 4; ++kc)
#pragma unroll
            for (int i = 0; i < 4; ++i)
                wf[fc][kc][i] = (_Float16)Wsrc[(16 * kc + 4 * grp + i) * 64 + f];
    }
    float bval[NF];
#pragma unroll
    for (int fc = 0; fc < NF; ++fc)
        bval[fc] = (DUAL && fc < NF / 2) ? bias[16 * fc + sub] : 0.0f;

    int wid = (blockIdx.x * blockDim.x + threadIdx.x) >> 6;
    int nw = (gridDim.x * blockDim.x) >> 6;
    int ntiles = N >> 4;                                 // N % 16 == 0

    for (int t = wid; t < ntiles; t += nw) {
        int r0 = t << 4;
        half4_t a[4];
#pragma unroll
        for (int kc = 0; kc < 4; ++kc) {
            float4 xv = *(const float4*)(X + (size_t)(r0 + sub) * 64 + 16 * kc + 4 * grp);
            a[kc][0] = (_Float16)xv.x; a[kc][1] = (_Float16)xv.y;
            a[kc][2] = (_Float16)xv.z; a[kc][3] = (_Float16)xv.w;
        }
        f32x4 acc[NF];
#pragma unroll
        for (int fc = 0; fc < NF; ++fc) {
            float b = bval[fc];
            acc[fc][0] = b; acc[fc][1] = b; acc[fc][2] = b; acc[fc][3] = b;
        }
#pragma unroll
        for (int fc = 0; fc < NF; ++fc)
#pragma unroll
            for (int kc = 0; kc < 4; ++kc)
                acc[fc] = __builtin_amdgcn_mfma_f32_16x16x16f16(a[kc], wf[fc][kc], acc[fc], 0, 0, 0);

        float4 sc = make_float4(1.f, 1.f, 1.f, 1.f);
        if (SCALE) sc = *(const float4*)(scale + r0 + 4 * grp);
        float scv[4] = {sc.x, sc.y, sc.z, sc.w};
#pragma unroll
        for (int fc = 0; fc < NF; ++fc) {
            __half* Y = (DUAL && fc >= NF / 2) ? YB : YA;
            int f = 16 * (DUAL ? (fc % (NF / 2)) : fc) + sub;
#pragma unroll
            for (int reg = 0; reg < 4; ++reg) {
                float v = acc[fc][reg];
                if (SCALE) v *= scv[reg];
                Y[(size_t)(r0 + 4 * grp + reg) * 64 + f] = __float2half_rn(v);
            }
        }
    }
}

// ---------------------------------------------------------------------------
// CSR segment-sum + finalize. Wave = 4 groups of 16 lanes; group g handles
// edges j ≡ g (mod 4); lane sub owns features 4sub..4sub+3 (one 8B fp16x4
// gather per edge). Up to 4 gathers in flight per group.
template <bool RELU>
__global__ void agg_csr_kernel(const float2* __restrict__ hs4,
                               const int* __restrict__ off, const int* __restrict__ deg,
                               const int* __restrict__ srcIdx,
                               const float* __restrict__ dinv, const float* __restrict__ b,
                               float4* __restrict__ out, int N) {
    int lane = threadIdx.x & 63;
    int n = blockIdx.x * (blockDim.x >> 6) + (threadIdx.x >> 6);
    if (n >= N) return;
    int g = lane >> 4;
    int sub = lane & 15;
    int o = off[n];
    int d = deg[n];
    float4 acc = make_float4(0.f, 0.f, 0.f, 0.f);
    if (g == 0) {                                        // self loop once
        float2 raw = hs4[(size_t)n * 16 + sub];
        float2 a01 = __half22float2(*(const __half2*)&raw.x);
        float2 a23 = __half22float2(*(const __half2*)&raw.y);
        acc.x = a01.x; acc.y = a01.y; acc.z = a23.x; acc.w = a23.y;
    }
    int j = g;
    for (; j + 12 < d; j += 16) {                        // 4 gathers in flight / group
        int s0 = srcIdx[o + j],     s1 = srcIdx[o + j + 4];
        int s2 = srcIdx[o + j + 8], s3 = srcIdx[o + j + 12];
        float2 v0 = hs4[(size_t)s0 * 16 + sub];
        float2 v1 = hs4[(size_t)s1 * 16 + sub];
        float2 v2 = hs4[(size_t)s2 * 16 + sub];
        float2 v3 = hs4[(size_t)s3 * 16 + sub];
        float2 a01 = __half22float2(*(const __half2*)&v0.x);
        float2 a23 = __half22float2(*(const __half2*)&v0.y);
        float2 b01 = __half22float2(*(const __half2*)&v1.x);
        float2 b23 = __half22float2(*(const __half2*)&v1.y);
        float2 c01 = __half22float2(*(const __half2*)&v2.x);
        float2 c23 = __half22float2(*(const __half2*)&v2.y);
        float2 d01 = __half22float2(*(const __half2*)&v3.x);
        float2 d23 = __half22float2(*(const __half2*)&v3.y);
        acc.x += (a01.x + b01.x) + (c01.x + d01.x);
        acc.y += (a01.y + b01.y) + (c01.y + d01.y);
        acc.z += (a23.x + b23.x) + (c23.x + d23.x);
        acc.w += (a23.y + b23.y) + (c23.y + d23.y);
    }
    for (; j + 4 < d; j += 8) {                          // 2 in flight
        int s0 = srcIdx[o + j];
        int s1 = srcIdx[o + j + 4];
        float2 v0 = hs4[(size_t)s0 * 16 + sub];
        float2 v1 = hs4[(size_t)s1 * 16 + sub];
        float2 a01 = __half22float2(*(const __half2*)&v0.x);
        float2 a23 = __half22float2(*(const __half2*)&v0.y);
        float2 b01 = __half22float2(*(const __half2*)&v1.x);
        float2 b23 = __half22float2(*(const __half2*)&v1.y);
        acc.x += a01.x + b01.x; acc.y += a01.y + b01.y;
        acc.z += a23.x + b23.x; acc.w += a23.y + b23.y;
    }
    for (; j < d; j += 4) {
        float2 v = hs4[(size_t)srcIdx[o + j] * 16 + sub];
        float2 a01 = __half22float2(*(const __half2*)&v.x);
        float2 a23 = __half22float2(*(const __half2*)&v.y);
        acc.x += a01.x; acc.y += a01.y; acc.z += a23.x; acc.w += a23.y;
    }
    acc.x += __shfl_xor(acc.x, 16); acc.y += __shfl_xor(acc.y, 16);
    acc.z += __shfl_xor(acc.z, 16); acc.w += __shfl_xor(acc.w, 16);
    acc.x += __shfl_xor(acc.x, 32); acc.y += __shfl_xor(acc.y, 32);
    acc.z += __shfl_xor(acc.z, 32); acc.w += __shfl_xor(acc.w, 32);
    if (g == 0) {
        float dv = dinv[n];
        float4 bb = ((const float4*)b)[sub];
        float4 v;
        v.x = dv * acc.x + bb.x; v.y = dv * acc.y + bb.y;
        v.z = dv * acc.z + bb.z; v.w = dv * acc.w + bb.w;
        if (RELU) {
            v.x = fmaxf(v.x, 0.f); v.y = fmaxf(v.y, 0.f);
            v.z = fmaxf(v.z, 0.f); v.w = fmaxf(v.w, 0.f);
        }
        out[(size_t)n * 16 + sub] = v;
    }
}

// ---------------------------------------------------------------------------
// edge MLP via mfma_f32_16x16x16_f16 (K=16). One wave = 16 edges.
// Lane (grp,sub): A: m=sub,k=4grp+i ; B: n=sub(edge),k=4grp+i ;
// D: n=sub, m=4grp+reg -> lane's hidden units h = 16grp+4reg+c, contiguous
// halves 16grp..16grp+15 of P[row]/Q[col] (two 16B loads each), fused as C-in.
__global__ void edge_mlp5_kernel(const __half* __restrict__ P16, const __half* __restrict__ Q16,
                                 const int* __restrict__ row, const int* __restrict__ col,
                                 const float4* __restrict__ eAtt4,
                                 const float* __restrict__ mW1,
                                 const float* __restrict__ mW2, const float* __restrict__ mb2,
                                 float* __restrict__ out, int E) {
    int lane = threadIdx.x & 63;
    int grp = lane >> 4;
    int sub = lane & 15;

    half4_t aC0, aC1, aC2, aC3;
#pragma unroll
    for (int i = 0; i < 4; ++i) {
        const float* crow = mW1 + (size_t)(128 + 4 * grp + i) * 64 + 4 * sub;
        aC0[i] = (_Float16)crow[0];
        aC1[i] = (_Float16)crow[1];
        aC2[i] = (_Float16)crow[2];
        aC3[i] = (_Float16)crow[3];
    }
    float4 w20 = ((const float4*)mW2)[4 * grp + 0];
    float4 w21 = ((const float4*)mW2)[4 * grp + 1];
    float4 w22 = ((const float4*)mW2)[4 * grp + 2];
    float4 w23 = ((const float4*)mW2)[4 * grp + 3];
    float b2v = mb2[0];

    int wid = (blockIdx.x * blockDim.x + threadIdx.x) >> 6;
    int nw = (gridDim.x * blockDim.x) >> 6;
    const int ntiles = E >> 4;

    int rN = 0, cN = 0;
    if (wid < ntiles) { rN = row[(wid << 4) + sub]; cN = col[(wid << 4) + sub]; }

    for (int t = wid; t < ntiles; t += nw) {
        int e0 = t << 4;
        int r = rN, cc = cN;
        int tn = t + nw;
        if (tn < ntiles) { rN = row[(tn << 4) + sub]; cN = col[(tn << 4) + sub]; }

        float4 ef = eAtt4[(size_t)e0 * 4 + (size_t)sub * 4 + grp];
        half4_t bf;
        bf[0] = (_Float16)ef.x; bf[1] = (_Float16)ef.y;
        bf[2] = (_Float16)ef.z; bf[3] = (_Float16)ef.w;

        const half8_t* pr = (const half8_t*)(P16 + (size_t)r * 64 + grp * 16);
        const half8_t* qr = (const half8_t*)(Q16 + (size_t)cc * 64 + grp * 16);
        half8_t ph0 = pr[0], ph1 = pr[1];
        half8_t qh0 = qr[0], qh1 = qr[1];

        f32x4 cin0 = {(float)ph0[0] + (float)qh0[0], (float)ph0[4] + (float)qh0[4],
                      (float)ph1[0] + (float)qh1[0], (float)ph1[4] + (float)qh1[4]};
        f32x4 cin1 = {(float)ph0[1] + (float)qh0[1], (float)ph0[5] + (float)qh0[5],
                      (float)ph1[1] + (float)qh1[1], (float)ph1[5] + (float)qh1[5]};
        f32x4 cin2 = {(float)ph0[2] + (float)qh0[2], (float)ph0[6] + (float)qh0[6],
                      (float)ph1[2] + (float)qh1[2], (float)ph1[6] + (float)qh1[6]};
        f32x4 cin3 = {(float)ph0[3] + (float)qh0[3], (float)ph0[7] + (float)qh0[7],
                      (float)ph1[3] + (float)qh1[3], (float)ph1[7] + (float)qh1[7]};

        f32x4 d0 = __builtin_amdgcn_mfma_f32_16x16x16f16(aC0, bf, cin0, 0, 0, 0);
        f32x4 d1 = __builtin_amdgcn_mfma_f32_16x16x16f16(aC1, bf, cin1, 0, 0, 0);
        f32x4 d2 = __builtin_amdgcn_mfma_f32_16x16x16f16(aC2, bf, cin2, 0, 0, 0);
        f32x4 d3 = __builtin_amdgcn_mfma_f32_16x16x16f16(aC3, bf, cin3, 0, 0, 0);

        float tacc = fmaxf(d0[0], 0.f) * w20.x + fmaxf(d0[1], 0.f) * w21.x
                   + fmaxf(d0[2], 0.f) * w22.x + fmaxf(d0[3], 0.f) * w23.x;
        tacc += fmaxf(d1[0], 0.f) * w20.y + fmaxf(d1[1], 0.f) * w21.y
              + fmaxf(d1[2], 0.f) * w22.y + fmaxf(d1[3], 0.f) * w23.y;
        tacc += fmaxf(d2[0], 0.f) * w20.z + fmaxf(d2[1], 0.f) * w21.z
              + fmaxf(d2[2], 0.f) * w22.z + fmaxf(d2[3], 0.f) * w23.z;
        tacc += fmaxf(d3[0], 0.f) * w20.w + fmaxf(d3[1], 0.f) * w21.w
              + fmaxf(d3[2], 0.f) * w22.w + fmaxf(d3[3], 0.f) * w23.w;

        tacc += __shfl_xor(tacc, 16);
        tacc += __shfl_xor(tacc, 32);
        if (grp == 0) out[e0 + sub] = tacc + b2v;
    }
}

// ---------------------------------------------------------------------------
extern "C" void kernel_launch(void* const* d_in, const int* in_sizes, int n_in,
                              void* d_out, int out_size, void* d_ws, size_t ws_size,
                              hipStream_t stream) {
    const float* x    = (const float*)d_in[0];   // [N, 64]
    const int*   eIdx = (const int*)d_in[1];     // [2, E]
    const float* eAtt = (const float*)d_in[2];   // [E, 16]
    const float* W1   = (const float*)d_in[3];
    const float* b1   = (const float*)d_in[4];
    const float* W2   = (const float*)d_in[5];
    const float* b2   = (const float*)d_in[6];
    const float* mW1  = (const float*)d_in[7];   // [144,64]: A(0:64), B(64:128), C(128:144)
    const float* mb1  = (const float*)d_in[8];
    const float* mW2  = (const float*)d_in[9];
    const float* mb2  = (const float*)d_in[10];
    float* out = (float*)d_out;                  // [E]

    const int N = N_NODES;
    const int E = N_EDGES;
    const int* row = eIdx;
    const int* col = eIdx + E;

    // workspace layout (all offsets multiples of 16B)
    int*    deg_i  = (int*)d_ws;                        // N
    int*    cnt    = deg_i + N;                         // N
    int*    off    = cnt + N;                           // N
    int*    bsum   = off + N;                           // 256
    float*  dinv   = (float*)(bsum + 256);              // N
    int*    srcIdx = (int*)(dinv + N);                  // E
    __half* h16    = (__half*)(srcIdx + ((E + 63) & ~63)); // N*64*2 halves
    float*  bufB   = (float*)(h16 + (size_t)2 * N * 64);   // N*64 f32
    __half* P16    = h16;
    __half* Q16    = h16 + (size_t)N * 64;

    const int aggBlocks  = (N + 3) / 4;
    const int scanBlocks = (N + 255) / 256;

    // --- CSR build ---
    hipMemsetAsync(deg_i, 0, N * sizeof(int), stream);
    deg_kernel<<<(E + 255) / 256, 256, 0, stream>>>(col, deg_i, E);
    scanA_kernel<<<scanBlocks, 256, 0, stream>>>(deg_i, off, bsum, N);
    scanB_kernel<<<1, 256, 0, stream>>>(bsum, scanBlocks);
    scanC_kernel<<<scanBlocks, 256, 0, stream>>>(deg_i, off, bsum, dinv, cnt, N);
    scatter_slice_kernel<<<384 * NSLICE, 256, 0, stream>>>(row, col, cnt, srcIdx, E);

    // --- layer 1: hs1 = half((x@W1)*dinv) ; agg -> bufB ---
    gemm_mfma_kernel<4, true, false><<<800, 256, 0, stream>>>(
        x, W1, W1, dinv, nullptr, h16, h16, N);
    agg_csr_kernel<true><<<aggBlocks, 256, 0, stream>>>(
        (const float2*)h16, off, deg_i, srcIdx, dinv, b1, (float4*)bufB, N);

    // --- layer 2 ---
    gemm_mfma_kernel<4, true, false><<<800, 256, 0, stream>>>(
        bufB, W2, W2, dinv, nullptr, h16, h16, N);
    agg_csr_kernel<false><<<aggBlocks, 256, 0, stream>>>(
        (const float2*)h16, off, deg_i, srcIdx, dinv, b2, (float4*)bufB, N);

    // --- edge MLP decomposition: P16 = h2@A + mb1, Q16 = h2@B (dual MFMA GEMM) ---
    gemm_mfma_kernel<8, false, true><<<800, 256, 0, stream>>>(
        bufB, mW1, mW1 + 64 * 64, nullptr, mb1, P16, Q16, N);

    edge_mlp5_kernel<<<2048, 256, 0, stream>>>(
        P16, Q16, row, col, (const float4*)eAtt,
        mW1, mW2, mb2, out, E);
}